// Round 4
// baseline (154.271 us; speedup 1.0000x reference)
//
#include <hip/hip_runtime.h>
#include <hip/hip_bf16.h>
#include <hip/hip_fp16.h>

// B=16, N=512, D=512, H=8, DH=64, PD=9, HID=32
#define NN 512
#define HH 8
#define DHH 64

typedef __attribute__((ext_vector_type(8))) short short8v;
typedef __attribute__((ext_vector_type(8))) unsigned short ushort8v;
typedef __attribute__((ext_vector_type(4))) unsigned short ushort4v;
typedef __attribute__((ext_vector_type(4))) float f32x4;
typedef __attribute__((ext_vector_type(8))) _Float16 f16x8;
typedef __attribute__((ext_vector_type(4))) _Float16 f16x4;

__device__ __forceinline__ unsigned short f2bf(float x) {
  unsigned u = __builtin_bit_cast(unsigned, x);
  u += 0x7FFFu + ((u >> 16) & 1u);
  return (unsigned short)(u >> 16);
}
__device__ __forceinline__ int swz64(int r, int cb) { return r * 64 + (cb ^ (((r >> 1) & 3) << 4)); }
__device__ __forceinline__ int swz128(int r, int cb) { return r * 128 + (cb ^ ((r & 7) << 4)); }

// ---------------- fp32 -> bf16 elementwise ----------------
__global__ __launch_bounds__(256) void cvt_bf(const float* __restrict__ src,
                                              unsigned short* __restrict__ dst, int n) {
  int i = (blockIdx.x * 256 + threadIdx.x) * 4;
  if (i < n) {
    float4 v = *(const float4*)&src[i];
    ushort4v o;
    o[0] = f2bf(v.x); o[1] = f2bf(v.y); o[2] = f2bf(v.z); o[3] = f2bf(v.w);
    *(ushort4v*)&dst[i] = o;
  }
}

// ---------------- transpose + cvt: src fp32 [R][C] -> dst bf16 [C][R] ----------------
__global__ __launch_bounds__(256) void transpose_cvt(const float* __restrict__ src,
                                                     unsigned short* __restrict__ dst,
                                                     int R, int C) {
  __shared__ float t[32][33];
  const int r0 = blockIdx.x * 32, c0 = blockIdx.y * 32;
  const int rr = threadIdx.x >> 3, c4 = (threadIdx.x & 7) * 4;
  float4 v = *(const float4*)&src[(size_t)(r0 + rr) * C + c0 + c4];
  t[rr][c4 + 0] = v.x; t[rr][c4 + 1] = v.y; t[rr][c4 + 2] = v.z; t[rr][c4 + 3] = v.w;
  __syncthreads();
  ushort4v o;
#pragma unroll
  for (int e = 0; e < 4; ++e) o[e] = f2bf(t[c4 + e][rr]);
  *(ushort4v*)&dst[(size_t)(c0 + rr) * R + r0 + c4] = o;
}

// ---------------- shared 128x128 bf16 MFMA GEMM body (BK=32, 4 waves) ----------------
__device__ __forceinline__ void gemm128_body(const unsigned short* __restrict__ A,
                                             const unsigned short* __restrict__ Bt,
                                             int ldk, int m0, int n0,
                                             f32x4 acc[4][4], unsigned char* smem) {
  const int tid = threadIdx.x, lane = tid & 63, wid = tid >> 6;
  const int wm = wid >> 1, wn = wid & 1;
  int aoff[4], boff[4];
#pragma unroll
  for (int i = 0; i < 4; ++i) {
    aoff[i] = swz64(wm * 64 + i * 16 + (lane & 15), (lane >> 4) * 16);
    boff[i] = 8192 + swz64(wn * 64 + i * 16 + (lane & 15), (lane >> 4) * 16);
  }
  for (int k0 = 0; k0 < ldk; k0 += 32) {
#pragma unroll
    for (int p = 0; p < 2; ++p) {
      const int idx = p * 256 + tid;
      const int r = idx >> 2, cg = idx & 3;
      ushort8v av = *(const ushort8v*)&A[(size_t)(m0 + r) * ldk + k0 + cg * 8];
      *(ushort8v*)&smem[swz64(r, cg * 16)] = av;
      ushort8v bv = *(const ushort8v*)&Bt[(size_t)(n0 + r) * ldk + k0 + cg * 8];
      *(ushort8v*)&smem[8192 + swz64(r, cg * 16)] = bv;
    }
    __syncthreads();
    short8v a[4], b[4];
#pragma unroll
    for (int i = 0; i < 4; ++i) {
      a[i] = *(const short8v*)&smem[aoff[i]];
      b[i] = *(const short8v*)&smem[boff[i]];
    }
#pragma unroll
    for (int i = 0; i < 4; ++i)
#pragma unroll
      for (int j = 0; j < 4; ++j)
        acc[i][j] = __builtin_amdgcn_mfma_f32_16x16x32_bf16(a[i], b[j], acc[i][j], 0, 0, 0);
    __syncthreads();
  }
}

// ---------------- QKV GEMM -> q [bh][n][dh], k [bh][n][dh], v TRANSPOSED [bh][dh][n] ----------------
__global__ __launch_bounds__(256) void gemm_qkv(const unsigned short* __restrict__ A,
                                                const unsigned short* __restrict__ Bt,
                                                unsigned short* __restrict__ q,
                                                unsigned short* __restrict__ k,
                                                unsigned short* __restrict__ vt) {
  __shared__ unsigned char smem[16384];
  f32x4 acc[4][4];
  const f32x4 z = {0.f, 0.f, 0.f, 0.f};
#pragma unroll
  for (int i = 0; i < 4; ++i)
#pragma unroll
    for (int j = 0; j < 4; ++j) acc[i][j] = z;
  gemm128_body(A, Bt, 512, blockIdx.x * 128, blockIdx.y * 128, acc, smem);
  const int lane = threadIdx.x & 63, wid = threadIdx.x >> 6;
  const int wm = wid >> 1, wn = wid & 1;
#pragma unroll
  for (int i = 0; i < 4; ++i) {
    const int row0 = blockIdx.x * 128 + wm * 64 + i * 16 + ((lane >> 4) << 2);
#pragma unroll
    for (int j = 0; j < 4; ++j) {
      const int col = blockIdx.y * 128 + wn * 64 + j * 16 + (lane & 15);
      const int part = col >> 9, head = (col >> 6) & 7, dh = col & 63;
#pragma unroll
      for (int rr = 0; rr < 4; ++rr) {
        const int row = row0 + rr;
        const int b_ = row >> 9, n_ = row & 511;
        const unsigned short val = f2bf(acc[i][j][rr]);
        if (part == 0)
          q[(((b_ * HH + head) * NN) + n_) * DHH + dh] = val;
        else if (part == 1)
          k[(((b_ * HH + head) * NN) + n_) * DHH + dh] = val;
        else
          vt[(((b_ * HH + head) * DHH) + dh) * NN + n_] = val;
      }
    }
  }
}

// ---------------- out GEMM: ao_bf[8192][512] @ WoT[512][512]^T -> fp32 out (masked) ----------------
__global__ __launch_bounds__(256) void gemm_out(const unsigned short* __restrict__ A,
                                                const unsigned short* __restrict__ Bt,
                                                const int* __restrict__ msk,
                                                float* __restrict__ out) {
  __shared__ unsigned char smem[16384];
  f32x4 acc[4][4];
  const f32x4 z = {0.f, 0.f, 0.f, 0.f};
#pragma unroll
  for (int i = 0; i < 4; ++i)
#pragma unroll
    for (int j = 0; j < 4; ++j) acc[i][j] = z;
  gemm128_body(A, Bt, 512, blockIdx.x * 128, blockIdx.y * 128, acc, smem);
  const int lane = threadIdx.x & 63, wid = threadIdx.x >> 6;
  const int wm = wid >> 1, wn = wid & 1;
#pragma unroll
  for (int i = 0; i < 4; ++i) {
    const int row0 = blockIdx.x * 128 + wm * 64 + i * 16 + ((lane >> 4) << 2);
#pragma unroll
    for (int j = 0; j < 4; ++j) {
      const int col = blockIdx.y * 128 + wn * 64 + j * 16 + (lane & 15);
#pragma unroll
      for (int rr = 0; rr < 4; ++rr) {
        const int row = row0 + rr;
        const float mm = (msk[row] != 0) ? 1.f : 0.f;
        out[(size_t)row * 512 + col] = acc[i][j][rr] * mm;
      }
    }
  }
}

// ---------------- FUSED pairwise-bias MLP + flash attention ----------------
// block = (it: 16 q-rows, b). 512 threads = 8 waves; wave w = head w.
// Per 64-j tile: all waves cooperatively compute bias[16 i][64 j] for ALL heads
// (f16 MFMA MLP, shared via double-buffered LDS), then each wave does its head's
// QK^T (+bias +mask) -> online softmax -> PV with V^T B-frags from global/L2.
__global__ __launch_bounds__(512, 4) void attn_bias_fused(
    const unsigned short* __restrict__ q, const unsigned short* __restrict__ k,
    const unsigned short* __restrict__ vt, const float* __restrict__ vvec,
    const int* __restrict__ tti, const int* __restrict__ msk,
    const float* __restrict__ W1, const float* __restrict__ b1,
    const float* __restrict__ W2, const float* __restrict__ b2,
    unsigned short* __restrict__ ao) {
  __shared__ float sv[NN][4];
  __shared__ int stt[NN];
  __shared__ float smask[NN];
  __shared__ _Float16 bias_lds[2][HH][16][68];  // [dbuf][head][i][j(64)+pad]
  __shared__ _Float16 hbuf[HH][16 * 40];        // per-wave MLP transpose
  __shared__ unsigned char ps[HH][2048];        // per-wave P tile (swz128)
  const int tid = threadIdx.x, lane = tid & 63, w = tid >> 6;
  const int l16 = lane & 15, lg = lane >> 4;
  const int it = blockIdx.x, b_ = blockIdx.y;
  const int i0 = it * 16;
  for (int idx = tid; idx < NN; idx += 512) {
    *(float4*)&sv[idx][0] = *(const float4*)&vvec[(b_ * NN + idx) * 4];
    stt[idx] = tti[idx];
    smask[idx] = (msk[b_ * NN + idx] != 0) ? 0.f : -1e30f;
  }
  // MLP weight fragments (wave-redundant broadcast loads)
  f16x8 w1f[2], w2f;
#pragma unroll
  for (int t = 0; t < 2; ++t)
#pragma unroll
    for (int e = 0; e < 8; ++e) {
      const int kk = lg * 8 + e;
      w1f[t][e] = (kk < 9) ? (_Float16)W1[kk * 32 + t * 16 + l16] : (_Float16)0.f;
    }
#pragma unroll
  for (int e = 0; e < 8; ++e)
    w2f[e] = (l16 < 8) ? (_Float16)W2[(lg * 8 + e) * 8 + l16] : (_Float16)0.f;
  const float b1v0 = b1[l16], b1v1 = b1[16 + l16];
  const float b2v = (l16 < 8) ? b2[l16] : 0.f;
  // per-head bases + Q fragments
  const unsigned short* qb = q + ((size_t)(b_ * HH + w) * NN + i0) * DHH;
  const unsigned short* kb = k + (size_t)(b_ * HH + w) * NN * DHH;
  const unsigned short* vtb = vt + (size_t)(b_ * HH + w) * DHH * NN;
  short8v qf[2];
#pragma unroll
  for (int kc = 0; kc < 2; ++kc)
    qf[kc] = *(const short8v*)&qb[l16 * DHH + kc * 32 + lg * 8];
  f32x4 acc[4];
  const f32x4 z = {0.f, 0.f, 0.f, 0.f};
#pragma unroll
  for (int d = 0; d < 4; ++d) acc[d] = z;
  float mrow[4], lrow[4];
#pragma unroll
  for (int r = 0; r < 4; ++r) { mrow[r] = -1e30f; lrow[r] = 0.f; }
  _Float16* hb = &hbuf[w][0];
  __syncthreads();
  int pbuf = 0;
  for (int j0 = 0; j0 < NN; j0 += 64) {
    // ---- Phase A: cooperative bias MLP for (i0..i0+15) x (j0..j0+63), all heads ----
    for (int tt = 0; tt < 8; ++tt) {
      const int il = w * 2 + (tt >> 2), jg = tt & 3;
      const float4 vi = *(const float4*)&sv[i0 + il][0];
      const int ti = stt[i0 + il];
      const int j = j0 + jg * 16 + l16;
      const float4 vj = *(const float4*)&sv[j][0];
      f16x8 af = {0, 0, 0, 0, 0, 0, 0, 0};
      if (lg == 0) {
        af[0] = (_Float16)(vi.x - vj.x); af[1] = (_Float16)(vi.y - vj.y);
        af[2] = (_Float16)(vi.z - vj.z); af[3] = (_Float16)(vi.w - vj.w);
        af[4] = (_Float16)(vi.x * vj.x); af[5] = (_Float16)(vi.y * vj.y);
        af[6] = (_Float16)(vi.z * vj.z); af[7] = (_Float16)(vi.w * vj.w);
      } else if (lg == 1) {
        af[0] = (ti == stt[j]) ? (_Float16)1.f : (_Float16)0.f;
      }
      f32x4 h0 = {b1v0, b1v0, b1v0, b1v0};
      f32x4 h1 = {b1v1, b1v1, b1v1, b1v1};
      h0 = __builtin_amdgcn_mfma_f32_16x16x32_f16(af, w1f[0], h0, 0, 0, 0);
      h1 = __builtin_amdgcn_mfma_f32_16x16x32_f16(af, w1f[1], h1, 0, 0, 0);
#pragma unroll
      for (int r = 0; r < 4; ++r) {
        const int row = lg * 4 + r;
        hb[row * 40 + l16] = (_Float16)fmaxf(h0[r], 0.f);
        hb[row * 40 + 16 + l16] = (_Float16)fmaxf(h1[r], 0.f);
      }
      f16x8 af2 = *(const f16x8*)&hb[l16 * 40 + lg * 8];
      f32x4 o = {b2v, b2v, b2v, b2v};
      o = __builtin_amdgcn_mfma_f32_16x16x32_f16(af2, w2f, o, 0, 0, 0);
      if (l16 < 8) {
        f16x4 pk;
#pragma unroll
        for (int r = 0; r < 4; ++r) pk[r] = (_Float16)o[r];
        *(f16x4*)&bias_lds[pbuf][l16][il][jg * 16 + lg * 4] = pk;
      }
    }
    __syncthreads();  // bias tile ready (and prev tile's reads done via dbuf)
    // ---- Phase B: attention for head w ----
    f32x4 s[4];
#pragma unroll
    for (int jt = 0; jt < 4; ++jt) {
      const unsigned short* kr = &kb[(j0 + jt * 16 + l16) * DHH + lg * 8];
      short8v kf0 = *(const short8v*)&kr[0];
      short8v kf1 = *(const short8v*)&kr[32];
      f32x4 t = z;
      t = __builtin_amdgcn_mfma_f32_16x16x32_bf16(qf[0], kf0, t, 0, 0, 0);
      t = __builtin_amdgcn_mfma_f32_16x16x32_bf16(qf[1], kf1, t, 0, 0, 0);
      s[jt] = t;
    }
#pragma unroll
    for (int jt = 0; jt < 4; ++jt) {
      const int jcol = j0 + jt * 16 + l16;
      const float mk = smask[jcol];
#pragma unroll
      for (int r = 0; r < 4; ++r) {
        const float bv = (float)bias_lds[pbuf][w][lg * 4 + r][jt * 16 + l16];
        s[jt][r] = fmaf(s[jt][r], 0.125f, bv) + mk;
      }
    }
    float alpha[4];
#pragma unroll
    for (int r = 0; r < 4; ++r) {
      float tm = fmaxf(fmaxf(s[0][r], s[1][r]), fmaxf(s[2][r], s[3][r]));
      tm = fmaxf(tm, __shfl_xor(tm, 1));
      tm = fmaxf(tm, __shfl_xor(tm, 2));
      tm = fmaxf(tm, __shfl_xor(tm, 4));
      tm = fmaxf(tm, __shfl_xor(tm, 8));
      const float mn = fmaxf(mrow[r], tm);
      alpha[r] = __expf(mrow[r] - mn);
      mrow[r] = mn;
      float ts = 0.f;
#pragma unroll
      for (int jt = 0; jt < 4; ++jt) {
        const float p = __expf(s[jt][r] - mn);
        s[jt][r] = p;
        ts += p;
      }
      ts += __shfl_xor(ts, 1);
      ts += __shfl_xor(ts, 2);
      ts += __shfl_xor(ts, 4);
      ts += __shfl_xor(ts, 8);
      lrow[r] = lrow[r] * alpha[r] + ts;
    }
#pragma unroll
    for (int d = 0; d < 4; ++d)
#pragma unroll
      for (int r = 0; r < 4; ++r) acc[d][r] *= alpha[r];
    // P -> bf16 -> per-wave LDS (proven swz128, wave-local)
#pragma unroll
    for (int jt = 0; jt < 4; ++jt)
#pragma unroll
      for (int r = 0; r < 4; ++r)
        *(unsigned short*)&ps[w][swz128(lg * 4 + r, jt * 32 + 2 * l16)] = f2bf(s[jt][r]);
    short8v pf[2];
#pragma unroll
    for (int kc = 0; kc < 2; ++kc)
      pf[kc] = *(const short8v*)&ps[w][swz128(l16, kc * 64 + lg * 16)];
    // PV: B-frags straight from global V^T (L2-resident)
#pragma unroll
    for (int d = 0; d < 4; ++d) {
      const unsigned short* vr = &vtb[(size_t)(d * 16 + l16) * NN + j0 + lg * 8];
      short8v vf0 = *(const short8v*)&vr[0];
      short8v vf1 = *(const short8v*)&vr[32];
      acc[d] = __builtin_amdgcn_mfma_f32_16x16x32_bf16(pf[0], vf0, acc[d], 0, 0, 0);
      acc[d] = __builtin_amdgcn_mfma_f32_16x16x32_bf16(pf[1], vf1, acc[d], 0, 0, 0);
    }
    pbuf ^= 1;
  }
  // epilogue: normalize, store attn_out bf16 [b][n][h*64+dh]
#pragma unroll
  for (int d = 0; d < 4; ++d) {
#pragma unroll
    for (int r = 0; r < 4; ++r) {
      const int row = i0 + lg * 4 + r;
      ao[(size_t)(b_ * NN + row) * 512 + w * DHH + d * 16 + l16] =
          f2bf(acc[d][r] / lrow[r]);
    }
  }
}

extern "C" void kernel_launch(void* const* d_in, const int* in_sizes, int n_in,
                              void* d_out, int out_size, void* d_ws, size_t ws_size,
                              hipStream_t stream) {
  const float* h     = (const float*)d_in[0];
  const float* v     = (const float*)d_in[1];
  const int*   m     = (const int*)d_in[2];
  const int*   tti   = (const int*)d_in[3];
  const float* W_qkv = (const float*)d_in[4];
  const float* W_out = (const float*)d_in[5];
  const float* W1    = (const float*)d_in[6];
  const float* b1    = (const float*)d_in[7];
  const float* W2    = (const float*)d_in[8];
  const float* b2    = (const float*)d_in[9];
  float* out = (float*)d_out;
  unsigned char* ws = (unsigned char*)d_ws;

  unsigned short* h_bf  = (unsigned short*)(ws + 0);
  unsigned short* q_bf  = (unsigned short*)(ws + 8388608);
  unsigned short* k_bf  = (unsigned short*)(ws + 16777216);
  unsigned short* vt_bf = (unsigned short*)(ws + 25165824);
  unsigned short* ao_bf = (unsigned short*)(ws + 33554432);
  unsigned short* WqT   = (unsigned short*)(ws + 41943040);
  unsigned short* WoT   = (unsigned short*)(ws + 43515904);

  cvt_bf<<<4096, 256, 0, stream>>>(h, h_bf, 16 * NN * 512);
  transpose_cvt<<<dim3(16, 48), 256, 0, stream>>>(W_qkv, WqT, 512, 1536);
  transpose_cvt<<<dim3(16, 16), 256, 0, stream>>>(W_out, WoT, 512, 512);
  gemm_qkv<<<dim3(64, 12), 256, 0, stream>>>(h_bf, WqT, q_bf, k_bf, vt_bf);
  attn_bias_fused<<<dim3(32, 16), 512, 0, stream>>>(q_bf, k_bf, vt_bf, v, tti, m,
                                                    W1, b1, W2, b2, ao_bf);
  gemm_out<<<dim3(64, 4), 256, 0, stream>>>(ao_bf, WoT, m, out);
}